// Round 7
// baseline (485.926 us; speedup 1.0000x reference)
//
#include <hip/hip_runtime.h>

// LocalExpansion: out[b,h,(y,x),c,d] = in[b,h,(y+i-3,x+j-3),d], c = i*7+j,
// zero-filled outside the image. Pure gather+write, memory-bound on the
// 462 MB output write.
//
// CONTROL RUN: exact v1 source (the only version that has successfully
// benched — 483.6 us in round 1). Rounds 2-6 all died with "MI355X
// container failed twice" across four structurally different sources
// (4-deep unroll +/- nontemporal stores, 2-deep straight-line). If this
// control also fails, the environment is down. If it passes, bisect the
// delta one construct at a time next round.

#define KH 7
#define KW 7
#define HEIGHT 48
#define WIDTH 48
#define DDIM 64
#define NPIX (HEIGHT * WIDTH)   // 2304
#define KK (KH * KW)            // 49

__global__ __launch_bounds__(256) void local_expansion_kernel(
    const float* __restrict__ in, float* __restrict__ out) {
    // One thread per output float4. Grid sized exactly: total4 % 256 == 0.
    int idx4 = blockIdx.x * 256 + threadIdx.x;

    // idx4 = ((bh * NPIX + n) * KK + c) * 16 + d4
    int d4   = idx4 & 15;
    int rem  = idx4 >> 4;        // (bh*NPIX + n)*KK + c
    int c    = rem % KK;
    int rem2 = rem / KK;         // bh*NPIX + n
    int n    = rem2 % NPIX;
    int bh   = rem2 / NPIX;

    int y = n / WIDTH;
    int x = n - y * WIDTH;
    int i = c / KW;
    int j = c - i * KW;

    int sy = y + i - (KH - 1) / 2;
    int sx = x + j - (KW - 1) / 2;

    float4 v = make_float4(0.f, 0.f, 0.f, 0.f);
    if ((unsigned)sy < (unsigned)HEIGHT && (unsigned)sx < (unsigned)WIDTH) {
        int in4 = (bh * NPIX + sy * WIDTH + sx) * (DDIM / 4) + d4;
        v = ((const float4*)in)[in4];
    }
    ((float4*)out)[idx4] = v;
}

extern "C" void kernel_launch(void* const* d_in, const int* in_sizes, int n_in,
                              void* d_out, int out_size, void* d_ws, size_t ws_size,
                              hipStream_t stream) {
    const float* x = (const float*)d_in[0];
    float* out = (float*)d_out;

    // out_size = 2*8*2304*49*64 = 115,605,504 floats -> 28,901,376 float4s
    int total4 = out_size / 4;
    dim3 grid(total4 / 256);   // 112,896 blocks, exact
    local_expansion_kernel<<<grid, 256, 0, stream>>>(x, out);
}

// Round 8
// 460.286 us; speedup vs baseline: 1.0557x; 1.0557x over previous
//
#include <hip/hip_runtime.h>

// LocalExpansion: out[b,h,(y,x),c,d] = in[b,h,(y+i-3,x+j-3),d], c = i*7+j,
// zero-filled outside the image. Memory-movement kernel: 462 MB write,
// 9.4 MB input read 49x (cache-resident).
//
// v8 == v4 design: 4-deep MLP per wave, block-contiguous unroll — thread t
// of block b handles idx4 = b*1024 + u*256 + t, u=0..3. All 4 branchless
// loads (clamped addr + select) issue before the first store's waitcnt;
// every store instruction is 256-lane contiguous; each block writes one
// 16 KB contiguous span; 4x fewer waves than v1. v1 (one dependent
// load->store per thread) measured ~190 us vs the ~73 us write floor
// (harness fills prove 6.3 TB/s streaming stores on this chip).
// Rounds 2-6 failures were an infra outage (round-7 control reproduced v1).

#define KH 7
#define KW 7
#define HEIGHT 48
#define WIDTH 48
#define DDIM 64
#define NPIX (HEIGHT * WIDTH)   // 2304
#define KK (KH * KW)            // 49
#define UNROLL 4

__global__ __launch_bounds__(256) void local_expansion_kernel(
    const float* __restrict__ in, float* __restrict__ out) {
    int base4 = blockIdx.x * (256 * UNROLL) + threadIdx.x;

    float4 v[UNROLL];

#pragma unroll
    for (int u = 0; u < UNROLL; ++u) {
        int idx4 = base4 + u * 256;

        // idx4 = ((bh*NPIX + n)*KK + c)*16 + d4
        int d4   = idx4 & 15;
        int rem  = idx4 >> 4;
        int c    = rem % KK;
        int rem2 = rem / KK;
        int n    = rem2 % NPIX;
        int bh   = rem2 / NPIX;

        int y = n / WIDTH;
        int x = n - y * WIDTH;
        int i = c / KW;
        int j = c - i * KW;

        int sy = y + i - (KH - 1) / 2;
        int sx = x + j - (KW - 1) / 2;

        bool inb = ((unsigned)sy < (unsigned)HEIGHT) & ((unsigned)sx < (unsigned)WIDTH);

        // Branchless: clamp to a valid address, load unconditionally, select.
        int syc = min(max(sy, 0), HEIGHT - 1);
        int sxc = min(max(sx, 0), WIDTH - 1);
        int in4 = (bh * NPIX + syc * WIDTH + sxc) * (DDIM / 4) + d4;

        float4 t = ((const float4*)in)[in4];
        v[u] = inb ? t : make_float4(0.f, 0.f, 0.f, 0.f);
    }

#pragma unroll
    for (int u = 0; u < UNROLL; ++u) {
        ((float4*)out)[base4 + u * 256] = v[u];
    }
}

extern "C" void kernel_launch(void* const* d_in, const int* in_sizes, int n_in,
                              void* d_out, int out_size, void* d_ws, size_t ws_size,
                              hipStream_t stream) {
    const float* x = (const float*)d_in[0];
    float* out = (float*)d_out;

    // out_size = 115,605,504 floats -> 28,901,376 float4s; /(256*4) = 28,224 exact
    int total4 = out_size / 4;
    int blocks = total4 / (256 * UNROLL);
    local_expansion_kernel<<<dim3(blocks), 256, 0, stream>>>(x, out);
}